// Round 7
// baseline (279.411 us; speedup 1.0000x reference)
//
#include <hip/hip_runtime.h>
#include <hip/hip_bf16.h>
#include <stdint.h>

#define L_DIM 384
#define MD    256      // M_DIM
#define CC    32       // C
#define ZD    128      // Z_DIM
#define NB    512      // N (batch) = K of the big GEMM
#define K2    1024     // C*C
#define MROWS 12288    // L*C

typedef __attribute__((ext_vector_type(4)))  float f32x4;
typedef __attribute__((ext_vector_type(16))) float f32x16;
typedef __attribute__((ext_vector_type(8)))  short bf16x8;

typedef __attribute__((address_space(1))) unsigned char* gcp;
typedef __attribute__((address_space(3))) unsigned char* lcp;

#define SBAR()  __builtin_amdgcn_s_barrier()
#define VMW(n)  asm volatile("s_waitcnt vmcnt(" #n ")" ::: "memory")
#define PRIO1() __builtin_amdgcn_s_setprio(1)
#define PRIO0() __builtin_amdgcn_s_setprio(0)

__device__ __forceinline__ unsigned short f2bf(float x) {
    union { float f; unsigned u; } v; v.f = x;
    unsigned r = v.u + 0x7fffu + ((v.u >> 16) & 1u);   // round-to-nearest-even
    return (unsigned short)(r >> 16);
}

__device__ __forceinline__ uint2 pack4(unsigned short a, unsigned short b,
                                       unsigned short c, unsigned short d) {
    uint2 r; r.x = (unsigned)a | ((unsigned)b << 16);
    r.y = (unsigned)c | ((unsigned)d << 16); return r;
}

// ---------------------------------------------------------------------------
// prep: w3 -> MFMA B-fragment order w3frag[ks][zg][lane][8], k2' = b*32+a
// (b-major so op tile writes vectorize). w1/w2 -> wfrag for ln_proj.
__global__ __launch_bounds__(256) void prep_kernel(
    const float* __restrict__ w1, const float* __restrict__ w2,
    const float* __restrict__ w3,
    unsigned short* __restrict__ w3frag, unsigned short* __restrict__ wfrag)
{
    int idx = blockIdx.x * 256 + threadIdx.x;          // 147456 total
    if (idx < 131072) {
        int e = idx & 7, lane = (idx >> 3) & 63, zg = (idx >> 9) & 7, ks = idx >> 12;
        int k2p = ks * 32 + ((lane >> 4) << 3) + e;    // k2' = b*32 + a
        int wrow = (k2p & 31) * 32 + (k2p >> 5);       // = a*32 + b
        int z  = zg * 16 + (lane & 15);
        w3frag[idx] = f2bf(w3[(size_t)wrow * ZD + z]);
    } else {
        int j = idx - 131072;                           // 16384
        int e = j & 7, lane = (j >> 3) & 63, nf = (j >> 9) & 3, ks = j >> 11;
        int c = nf * 16 + (lane & 15);
        int d = ks * 32 + ((lane >> 4) << 3) + e;
        float v = (c < CC) ? w2[d * CC + c] : w1[d * CC + (c - CC)];
        wfrag[j] = f2bf(v);
    }
}

// ---------------------------------------------------------------------------
// Kernel A: LayerNorm + dual projection via MFMA.
// At: row-major K-contig [ia][n] (LDS staging in opm).
// Bt: 32x32-MFMA B-FRAGMENT order [f32=j][kc=n/16][lane][8]:
//     lane = b + 32*((n>>3)&1), elem = n&7  (col=lane&31, k=(lane>>5)*8+e).
__global__ __launch_bounds__(256, 4) void ln_proj_kernel(
    const float* __restrict__ mm, const float* __restrict__ gamma, const float* __restrict__ beta,
    const unsigned short* __restrict__ wfrag,
    const float* __restrict__ b1, const float* __restrict__ b2,
    unsigned short* __restrict__ At, unsigned short* __restrict__ Bt)
{
    __shared__ alignas(16) char o_b[32768];            // [64 rows][512 B] swizzled

    const int tid = threadIdx.x, wv = tid >> 6, lane = tid & 63;
    const int l0 = blockIdx.y * 2;
    const int n0 = blockIdx.x * 32;

    const int l_loc = wv >> 1;
    const int nbase = (wv & 1) << 4;
    const int l_g = l0 + l_loc;
    f32x4 g4 = *(const f32x4*)(gamma + lane * 4);
    f32x4 e4 = *(const f32x4*)(beta + lane * 4);

    #pragma unroll 4
    for (int r = 0; r < 16; ++r) {
        int row_loc = wv * 16 + r;
        int n_g = n0 + nbase + r;
        const float* src = mm + ((size_t)n_g * L_DIM + l_g) * MD + lane * 4;
        f32x4 x = *(const f32x4*)src;
        float s  = x[0] + x[1] + x[2] + x[3];
        float s2 = x[0]*x[0] + x[1]*x[1] + x[2]*x[2] + x[3]*x[3];
        #pragma unroll
        for (int off = 32; off > 0; off >>= 1) {
            s  += __shfl_xor(s,  off);
            s2 += __shfl_xor(s2, off);
        }
        float mu  = s * (1.0f / MD);
        float var = s2 * (1.0f / MD) - mu * mu;
        float rs  = rsqrtf(var + 1e-5f);
        unsigned short o0 = f2bf((x[0] - mu) * rs * g4[0] + e4[0]);
        unsigned short o1 = f2bf((x[1] - mu) * rs * g4[1] + e4[1]);
        unsigned short o2 = f2bf((x[2] - mu) * rs * g4[2] + e4[2]);
        unsigned short o3 = f2bf((x[3] - mu) * rs * g4[3] + e4[3]);
        *(uint2*)(o_b + row_loc * 512 + ((lane * 8) ^ ((row_loc & 7) << 4))) = pack4(o0, o1, o2, o3);
    }
    // wave-private rows -> no barrier needed

    f32x4 acc[4] = {{0,0,0,0},{0,0,0,0},{0,0,0,0},{0,0,0,0}};
    const int lrow = lane & 15;
    const int kq16 = (lane >> 4) << 4;
    const int arow = wv * 16 + lrow;
    #pragma unroll
    for (int ks = 0; ks < 8; ++ks) {
        bf16x8 a = *(const bf16x8*)(o_b + arow * 512 + ((ks * 64 + kq16) ^ ((arow & 7) << 4)));
        #pragma unroll
        for (int nf = 0; nf < 4; ++nf) {
            bf16x8 b = *(const bf16x8*)(wfrag + (size_t)((ks * 4 + nf) * 64 + lane) * 8);
            acc[nf] = __builtin_amdgcn_mfma_f32_16x16x32_bf16(a, b, acc[nf], 0, 0, 0);
        }
    }

    const int rr0 = wv * 16 + ((lane >> 4) << 2);
    const int n_gw = n0 + (rr0 & 31);                  // multiple of 4
    const int l_gw = l0 + (rr0 >> 5);
    #pragma unroll
    for (int nf = 0; nf < 4; ++nf) {
        int c = nf * 16 + lrow;
        float bias = (c < CC) ? b2[c] : b1[c - CC];
        uint2 pk = pack4(f2bf(acc[nf][0] + bias), f2bf(acc[nf][1] + bias),
                         f2bf(acc[nf][2] + bias), f2bf(acc[nf][3] + bias));
        if (c < CC) {
            *(uint2*)(At + (size_t)(l_gw * CC + c) * NB + n_gw) = pk;
        } else {
            int c31 = c - CC;
            size_t addr = (((size_t)l_gw * 32 + (n_gw >> 4)) * 64
                           + c31 + (((n_gw >> 3) & 1) << 5)) * 8 + (n_gw & 7);
            *(uint2*)(Bt + addr) = pk;
        }
    }
}

// ---------------------------------------------------------------------------
// Kernel B: 128x256 op-tile GEMM, 32x32x16 MFMA, BK=128 (16-slot swizzle ->
// 2-way-free ds_read), A in 2x32KB LDS dbuf (64KB -> 2 blocks/CU), B direct
// global->reg fragments prefetched 3 slots ahead. 1 SBAR per K-tile.
// Fused w3 epilogue: 32-pair op tile reuses the 64KB, R5-verified z path.
__global__ __launch_bounds__(512, 4) void opm_kernel(
    const unsigned short* __restrict__ At, const unsigned short* __restrict__ Bt,
    const unsigned short* __restrict__ w3frag, const float* __restrict__ b3,
    float* __restrict__ Z)
{
    __shared__ alignas(128) char smem[65536];          // A dbuf 2x32KB; epi: op tile
    char* const Ab = smem;

    const int tid = threadIdx.x, wv = tid >> 6, lane = tid & 63;

    // XCD-aware remap: 4608 blocks; XCD owns 12-i-tile band x all 48 j (j-major)
    const int lin = blockIdx.x;
    const int xcd = lin & 7, chunk = lin >> 3;         // chunk in [0,576)
    const int i0 = (xcd * 12 + (chunk % 12)) * 128;
    const int j0 = (chunk / 12) * 256;

    const int mrow = lane & 31;
    const int kb16 = (lane >> 5) << 4;                 // k byte offset 0/16
    const int swz  = (mrow & 15) << 4;                 // 16-slot XOR (2-way free)
    const int wr = (wv >> 2) * 64, wc = (wv & 3) * 64;
    const int fb0 = (j0 + wc) >> 5;

    // stage A tile t (128 rows x 256B): wave stages rows [wv*16, wv*16+16)
    auto stageA = [&](int t) {
        char* base = Ab + (t & 1) * 32768;
        #pragma unroll
        for (int q = 0; q < 4; ++q) {
            int r0 = wv * 16 + q * 4;
            int row = r0 + (lane >> 4);
            const unsigned short* gp = At + (size_t)(i0 + row) * NB + t * 128
                                       + (((lane & 15) ^ (row & 15)) << 3);
            __builtin_amdgcn_global_load_lds((gcp)gp, (lcp)(base + r0 * 256), 16, 0, 0);
        }
    };

    // B fragment pair for global slot s (= kc), cols wc..wc+63
    auto loadBp = [&](bf16x8* dst, int s) {
        #pragma unroll
        for (int nf = 0; nf < 2; ++nf)
            dst[nf] = *(const bf16x8*)(Bt + ((size_t)((fb0 + nf) * 32 + s) * 64 + lane) * 8);
    };

    f32x16 acc[2][2] = {};
    bf16x8 bv[4][2];                                    // ring-4, issue 3 ahead

    // prologue
    stageA(0); stageA(1);
    loadBp(bv[0], 0); loadBp(bv[1], 1); loadBp(bv[2], 2);
    VMW(10);                                            // drain stageA(0)
    SBAR();

    #pragma unroll
    for (int t = 0; t < 4; ++t) {
        const char* ab = Ab + (t & 1) * 32768;
        if (t >= 1 && t <= 2) stageA(t + 1);
        #pragma unroll
        for (int ks = 0; ks < 8; ++ks) {
            const int s = t * 8 + ks;
            bf16x8 av0 = *(const bf16x8*)(ab + (wr      + mrow) * 256 + ((ks * 32 + kb16) ^ swz));
            bf16x8 av1 = *(const bf16x8*)(ab + (wr + 32 + mrow) * 256 + ((ks * 32 + kb16) ^ swz));
            PRIO1();
            acc[0][0] = __builtin_amdgcn_mfma_f32_32x32x16_bf16(av0, bv[s & 3][0], acc[0][0], 0, 0, 0);
            acc[0][1] = __builtin_amdgcn_mfma_f32_32x32x16_bf16(av0, bv[s & 3][1], acc[0][1], 0, 0, 0);
            acc[1][0] = __builtin_amdgcn_mfma_f32_32x32x16_bf16(av1, bv[s & 3][0], acc[1][0], 0, 0, 0);
            acc[1][1] = __builtin_amdgcn_mfma_f32_32x32x16_bf16(av1, bv[s & 3][1], acc[1][1], 0, 0, 0);
            PRIO0();
            if (s + 3 < 32) loadBp(bv[(s + 3) & 3], s + 3);
        }
        if (t < 3) { VMW(6); SBAR(); }                  // stage(t+1) older than 3 newest B-pairs
    }
    __syncthreads();   // all waves done with A-LDS before op tile reuses smem

    // ---- fused w3 epilogue ----
    char* const opb = smem;                            // 32 pairs x 2048 B = 64 KB
    const int lrow = lane & 15;
    const int lq = lane >> 4;

    auto ldW = [&](int ks, int zg) -> bf16x8 {
        return *(const bf16x8*)(w3frag + (size_t)((ks * 8 + zg) * 64 + lane) * 8);
    };
    auto ldP = [&](int row, int ks) -> bf16x8 {
        int g = ks * 4 + lq;
        int b = g >> 2, jj = g & 3;
        int inner = (b * 64 + jj * 16) ^ (((b >> 1) & 7) << 4) ^ ((row & 7) << 4);
        return *(const bf16x8*)(opb + row * 2048 + inner);
    };

    const int pf  = wv & 1;
    const int zgb = (wv >> 1) * 2;
    const int row0 = pf * 16 + lrow;

    // early-issue first w3 loads (hide under op-write)
    bf16x8 wA0 = ldW(0, zgb), wA1 = ldW(0, zgb + 1);

    // write op tile (scaled bf16), b-major k2' = b*32+a, 8B vector stores.
    // 32x32 C/D layout: col = lane&31, row = (reg&3) + 8*(reg>>2) + 4*(lane>>5)
    const float scale = 1.0f / (float)NB;
    const int bcol = lane & 31;
    const int hq4  = (lane >> 5) << 2;
    #pragma unroll
    for (int mf = 0; mf < 2; ++mf) {
        #pragma unroll
        for (int nf = 0; nf < 2; ++nf) {
            int pl = (((wr + mf * 32) >> 5) << 3) | ((wc >> 5) + nf);
            int swp = (((bcol >> 1) & 7) << 4) ^ ((pl & 7) << 4);
            #pragma unroll
            for (int q = 0; q < 4; ++q) {
                int a0e = q * 8 + hq4;
                int inner = (bcol * 64 + a0e * 2) ^ swp;
                *(uint2*)(opb + pl * 2048 + inner) =
                    pack4(f2bf(acc[mf][nf][4*q+0] * scale), f2bf(acc[mf][nf][4*q+1] * scale),
                          f2bf(acc[mf][nf][4*q+2] * scale), f2bf(acc[mf][nf][4*q+3] * scale));
            }
        }
    }
    __syncthreads();

    // z-loop: 32 ks, 2 MFMA each; prefetch 1 ahead (w3 from L2, op from LDS)
    f32x4 acc2[2] = {};
    bf16x8 pA = ldP(row0, 0);
    for (int ks = 0; ks < 32; ++ks) {
        bf16x8 wN0 = {}, wN1 = {}, pN = {};
        if (ks + 1 < 32) {
            wN0 = ldW(ks + 1, zgb); wN1 = ldW(ks + 1, zgb + 1);
            pN  = ldP(row0, ks + 1);
        }
        PRIO1();
        acc2[0] = __builtin_amdgcn_mfma_f32_16x16x32_bf16(pA, wA0, acc2[0], 0, 0, 0);
        acc2[1] = __builtin_amdgcn_mfma_f32_16x16x32_bf16(pA, wA1, acc2[1], 0, 0, 0);
        PRIO0();
        wA0 = wN0; wA1 = wN1; pA = pN;
    }

    // write z
    const int pq = (lane >> 4) << 2;
    #pragma unroll
    for (int zi = 0; zi < 2; ++zi) {
        int zc = (zgb + zi) * 16 + lrow;
        float bias = b3[zc];
        #pragma unroll
        for (int rr = 0; rr < 4; ++rr) {
            int pl = pf * 16 + pq + rr;
            int ii = (i0 >> 5) + (pl >> 3);
            int jj = (j0 >> 5) + (pl & 7);
            Z[((size_t)ii * L_DIM + jj) * ZD + zc] = acc2[zi][rr] + bias;
        }
    }
}

// ---------------------------------------------------------------------------
extern "C" void kernel_launch(void* const* d_in, const int* in_sizes, int n_in,
                              void* d_out, int out_size, void* d_ws, size_t ws_size,
                              hipStream_t stream)
{
    const float* mm    = (const float*)d_in[0];
    const float* gamma = (const float*)d_in[1];
    const float* beta  = (const float*)d_in[2];
    const float* w1    = (const float*)d_in[3];
    const float* b1    = (const float*)d_in[4];
    const float* w2    = (const float*)d_in[5];
    const float* b2    = (const float*)d_in[6];
    const float* w3    = (const float*)d_in[7];
    const float* b3    = (const float*)d_in[8];

    unsigned short* At     = (unsigned short*)d_ws;                  // 12288x512
    unsigned short* Bt     = At + (size_t)MROWS * NB;                // frag order
    unsigned short* w3frag = Bt + (size_t)MROWS * NB;                // 131072
    unsigned short* wfrag  = w3frag + 131072;                        // 16384

    prep_kernel<<<576, 256, 0, stream>>>(w1, w2, w3, w3frag, wfrag);
    ln_proj_kernel<<<dim3(16, 192), 256, 0, stream>>>(mm, gamma, beta, wfrag, b1, b2, At, Bt);
    opm_kernel<<<4608, 512, 0, stream>>>(At, Bt, w3frag, b3, (float*)d_out);
}

// Round 9
// 260.046 us; speedup vs baseline: 1.0745x; 1.0745x over previous
//
#include <hip/hip_runtime.h>
#include <hip/hip_bf16.h>
#include <stdint.h>

#define L_DIM 384
#define MD    256      // M_DIM
#define CC    32       // C
#define ZD    128      // Z_DIM
#define NB    512      // N (batch) = K of the big GEMM
#define K2    1024     // C*C
#define MROWS 12288    // L*C

typedef __attribute__((ext_vector_type(4))) float  f32x4;
typedef __attribute__((ext_vector_type(8))) short  bf16x8;

typedef __attribute__((address_space(1))) unsigned char* gcp;
typedef __attribute__((address_space(3))) unsigned char* lcp;

#define SBAR()  __builtin_amdgcn_s_barrier()
#define LGKM0() asm volatile("s_waitcnt lgkmcnt(0)" ::: "memory")
#define VMW(n)  asm volatile("s_waitcnt vmcnt(" #n ")" ::: "memory")
#define PRIO1() __builtin_amdgcn_s_setprio(1)
#define PRIO0() __builtin_amdgcn_s_setprio(0)

__device__ __forceinline__ unsigned short f2bf(float x) {
    union { float f; unsigned u; } v; v.f = x;
    unsigned r = v.u + 0x7fffu + ((v.u >> 16) & 1u);   // round-to-nearest-even
    return (unsigned short)(r >> 16);
}

__device__ __forceinline__ uint2 pack4(unsigned short a, unsigned short b,
                                       unsigned short c, unsigned short d) {
    uint2 r; r.x = (unsigned)a | ((unsigned)b << 16);
    r.y = (unsigned)c | ((unsigned)d << 16); return r;
}

// ---------------------------------------------------------------------------
// prep: pack w3 into MFMA B-fragment order w3frag[ks][zg][lane][8] where the
// fragment k-index k2p encodes k2' = b*32 + a (b-major!), so the op tile can be
// written b-major (vectorized 8B stores). Original w3 row = a*C + b.
// Also pack w1/w2 into wfrag[ks][nf][lane][8] for ln_proj.
__global__ __launch_bounds__(256) void prep_kernel(
    const float* __restrict__ w1, const float* __restrict__ w2,
    const float* __restrict__ w3,
    unsigned short* __restrict__ w3frag, unsigned short* __restrict__ wfrag)
{
    int idx = blockIdx.x * 256 + threadIdx.x;          // 147456 total
    if (idx < 131072) {
        int e = idx & 7, lane = (idx >> 3) & 63, zg = (idx >> 9) & 7, ks = idx >> 12;
        int k2p = ks * 32 + ((lane >> 4) << 3) + e;    // k2' = b*32 + a
        int wrow = (k2p & 31) * 32 + (k2p >> 5);       // = a*32 + b
        int z  = zg * 16 + (lane & 15);
        w3frag[idx] = f2bf(w3[(size_t)wrow * ZD + z]);
    } else {
        int j = idx - 131072;                           // 16384
        int e = j & 7, lane = (j >> 3) & 63, nf = (j >> 9) & 3, ks = j >> 11;
        int c = nf * 16 + (lane & 15);
        int d = ks * 32 + ((lane >> 4) << 3) + e;
        float v = (c < CC) ? w2[d * CC + c] : w1[d * CC + (c - CC)];
        wfrag[j] = f2bf(v);
    }
}

// ---------------------------------------------------------------------------
// Kernel A: LayerNorm + dual projection (a = o@w2+b2, b = o@w1+b1) via MFMA.
__global__ __launch_bounds__(256, 4) void ln_proj_kernel(
    const float* __restrict__ mm, const float* __restrict__ gamma, const float* __restrict__ beta,
    const unsigned short* __restrict__ wfrag,
    const float* __restrict__ b1, const float* __restrict__ b2,
    unsigned short* __restrict__ At, unsigned short* __restrict__ Bt)
{
    __shared__ alignas(16) char o_b[32768];            // [64 rows][512 B] swizzled

    const int tid = threadIdx.x, wv = tid >> 6, lane = tid & 63;
    const int l0 = blockIdx.y * 2;
    const int n0 = blockIdx.x * 32;

    const int l_loc = wv >> 1;
    const int nbase = (wv & 1) << 4;
    const int l_g = l0 + l_loc;
    f32x4 g4 = *(const f32x4*)(gamma + lane * 4);
    f32x4 e4 = *(const f32x4*)(beta + lane * 4);

    #pragma unroll 4
    for (int r = 0; r < 16; ++r) {
        int row_loc = wv * 16 + r;
        int n_g = n0 + nbase + r;
        const float* src = mm + ((size_t)n_g * L_DIM + l_g) * MD + lane * 4;
        f32x4 x = *(const f32x4*)src;
        float s  = x[0] + x[1] + x[2] + x[3];
        float s2 = x[0]*x[0] + x[1]*x[1] + x[2]*x[2] + x[3]*x[3];
        #pragma unroll
        for (int off = 32; off > 0; off >>= 1) {
            s  += __shfl_xor(s,  off);
            s2 += __shfl_xor(s2, off);
        }
        float mu  = s * (1.0f / MD);
        float var = s2 * (1.0f / MD) - mu * mu;
        float rs  = rsqrtf(var + 1e-5f);
        unsigned short o0 = f2bf((x[0] - mu) * rs * g4[0] + e4[0]);
        unsigned short o1 = f2bf((x[1] - mu) * rs * g4[1] + e4[1]);
        unsigned short o2 = f2bf((x[2] - mu) * rs * g4[2] + e4[2]);
        unsigned short o3 = f2bf((x[3] - mu) * rs * g4[3] + e4[3]);
        *(uint2*)(o_b + row_loc * 512 + ((lane * 8) ^ ((row_loc & 7) << 4))) = pack4(o0, o1, o2, o3);
    }
    // wave-private rows -> no barrier needed

    f32x4 acc[4] = {{0,0,0,0},{0,0,0,0},{0,0,0,0},{0,0,0,0}};
    const int lrow = lane & 15;
    const int kq16 = (lane >> 4) << 4;
    const int arow = wv * 16 + lrow;
    #pragma unroll
    for (int ks = 0; ks < 8; ++ks) {
        bf16x8 a = *(const bf16x8*)(o_b + arow * 512 + ((ks * 64 + kq16) ^ ((arow & 7) << 4)));
        #pragma unroll
        for (int nf = 0; nf < 4; ++nf) {
            bf16x8 b = *(const bf16x8*)(wfrag + (size_t)((ks * 4 + nf) * 64 + lane) * 8);
            acc[nf] = __builtin_amdgcn_mfma_f32_16x16x32_bf16(a, b, acc[nf], 0, 0, 0);
        }
    }

    const int rr0 = wv * 16 + ((lane >> 4) << 2);
    const int n_gw = n0 + (rr0 & 31);
    const int l_gw = l0 + (rr0 >> 5);
    #pragma unroll
    for (int nf = 0; nf < 4; ++nf) {
        int c = nf * 16 + lrow;
        float bias = (c < CC) ? b2[c] : b1[c - CC];
        unsigned short ob0 = f2bf(acc[nf][0] + bias);
        unsigned short ob1 = f2bf(acc[nf][1] + bias);
        unsigned short ob2 = f2bf(acc[nf][2] + bias);
        unsigned short ob3 = f2bf(acc[nf][3] + bias);
        unsigned short* dst = ((c < CC) ? At : Bt) + (size_t)(l_gw * CC + (c & 31)) * NB + n_gw;
        *(uint2*)dst = pack4(ob0, ob1, ob2, ob3);
    }
}

// ---------------------------------------------------------------------------
// Kernel B: 256x256 op-tile GEMM, K=512, 8-phase schedule, counted vmcnt,
// peeled tail, XCD-swizzled blocks, fused w3 epilogue with one-zg-per-wave
// (minimum w3 L2 traffic) + ring-4 w3 / ring-2 P register pipelining.
__global__ __launch_bounds__(512, 2) void opm_kernel(
    const unsigned short* __restrict__ At, const unsigned short* __restrict__ Bt,
    const unsigned short* __restrict__ w3frag, const float* __restrict__ b3,
    float* __restrict__ Z)
{
    __shared__ alignas(128) char smem[131072];         // A:[2][256][64] B:[2][256][64]
    char* const Ab = smem;
    char* const Bb = smem + 65536;

    const int tid = threadIdx.x, wv = tid >> 6, lane = tid & 63;

    // T1: XCD-aware remap. 48 i-tiles = 8 XCDs x 6-wide i-bands; within an XCD
    // walk j-major so the 1.5 MB A-band stays L2-resident and B(j) is reused 6x.
    const int lin = blockIdx.y * 48 + blockIdx.x;
    const int xcd = lin & 7, chunk = lin >> 3;         // chunk in [0,288)
    const int i0 = (xcd * 6 + (chunk % 6)) * 256;
    const int j0 = (chunk / 6) * 256;

    const int lrow = lane & 15;
    const int kq16 = (lane >> 4) << 4;
    const int wr = (wv >> 2) * 128, wc = (wv & 3) * 64;

    auto stage = [&](const unsigned short* __restrict__ src, int tile0, int kt,
                     int half, int isA) {
        #pragma unroll
        for (int q = 0; q < 2; ++q) {
            int rl0 = q * 64 + wv * 8;
            int rl  = rl0 + (lane >> 3);
            int rc  = isA ? ((rl  & 63) + ((rl  >> 6) << 7) + half * 64)
                          : ((rl  & 31) + ((rl  >> 5) << 6) + half * 32);
            int rc0 = isA ? ((rl0 & 63) + ((rl0 >> 6) << 7) + half * 64)
                          : ((rl0 & 31) + ((rl0 >> 5) << 6) + half * 32);
            const unsigned short* g = src + (size_t)(tile0 + rc) * NB + kt * 64
                                      + (((lane & 7) ^ (lane >> 3)) << 3);
            char* l = (isA ? Ab : Bb) + (kt & 1) * 32768 + rc0 * 128;  // wave-uniform
            __builtin_amdgcn_global_load_lds((gcp)g, (lcp)l, 16, 0, 0);
        }
    };

    f32x4 acc[8][4] = {};
    bf16x8 av[8], bl[4], bh[4];

    auto rdA = [&](const char* ab, int qrow) {
        #pragma unroll
        for (int mfl = 0; mfl < 4; ++mfl) {
            int row = wr + qrow * 64 + mfl * 16 + lrow;
            const char* p = ab + row * 128;
            av[mfl*2+0] = *(const bf16x8*)(p + ((     kq16) ^ ((row & 7) << 4)));
            av[mfl*2+1] = *(const bf16x8*)(p + ((64 + kq16) ^ ((row & 7) << 4)));
        }
    };
    auto rdB = [&](const char* bb, int qcol, bf16x8* bv) {
        #pragma unroll
        for (int nfl = 0; nfl < 2; ++nfl) {
            int col = wc + qcol * 32 + nfl * 16 + lrow;
            const char* p = bb + col * 128;
            bv[nfl*2+0] = *(const bf16x8*)(p + ((     kq16) ^ ((col & 7) << 4)));
            bv[nfl*2+1] = *(const bf16x8*)(p + ((64 + kq16) ^ ((col & 7) << 4)));
        }
    };
    auto MM = [&](bf16x8* bv, int mbase, int nbase) {
        #pragma unroll
        for (int mfl = 0; mfl < 4; ++mfl)
            #pragma unroll
            for (int nfl = 0; nfl < 2; ++nfl)
                #pragma unroll
                for (int ks = 0; ks < 2; ++ks)
                    acc[mbase+mfl][nbase+nfl] = __builtin_amdgcn_mfma_f32_16x16x32_bf16(
                        av[mfl*2+ks], bv[nfl*2+ks], acc[mbase+mfl][nbase+nfl], 0, 0, 0);
    };

    // --- prologue: stage kt0 + kt1, retire kt0, keep kt1 in flight ---
    stage(At, i0, 0, 0, 1); stage(At, i0, 0, 1, 1);
    stage(Bt, j0, 0, 0, 0); stage(Bt, j0, 0, 1, 0);
    stage(At, i0, 1, 0, 1); stage(At, i0, 1, 1, 1);
    stage(Bt, j0, 1, 0, 0); stage(Bt, j0, 1, 1, 0);
    VMW(8);
    SBAR();

    const char* a0 = Ab;           const char* b0 = Bb;
    const char* a1 = Ab + 32768;   const char* b1 = Bb + 32768;

    // --- main loop: t = 0..2, K-tiles (2t, 2t+1), stages (2t+2, 2t+3) ---
    for (int t = 0; t < 3; ++t) {
        const int ktc = 2*t + 2, ktd = 2*t + 3;
        rdA(a0, 0); rdB(b0, 0, bl);
        SBAR(); LGKM0(); PRIO1(); MM(bl, 0, 0); PRIO0(); SBAR();
        rdB(b0, 1, bh); stage(At, i0, ktc, 0, 1);
        SBAR(); LGKM0(); PRIO1(); MM(bh, 0, 2); PRIO0(); SBAR();
        rdA(a0, 1); stage(Bt, j0, ktc, 0, 0);
        SBAR(); LGKM0(); PRIO1(); MM(bh, 4, 2); PRIO0(); SBAR();
        stage(Bt, j0, ktc, 1, 0);
        SBAR(); LGKM0(); PRIO1(); MM(bl, 4, 0); PRIO0(); VMW(6); SBAR();
        rdA(a1, 0); rdB(b1, 0, bl); stage(At, i0, ktc, 1, 1);
        SBAR(); LGKM0(); PRIO1(); MM(bl, 0, 0); PRIO0(); SBAR();
        rdB(b1, 1, bh); stage(At, i0, ktd, 0, 1);
        SBAR(); LGKM0(); PRIO1(); MM(bh, 0, 2); PRIO0(); SBAR();
        rdA(a1, 1); stage(Bt, j0, ktd, 0, 0);
        SBAR(); LGKM0(); PRIO1(); MM(bh, 4, 2); PRIO0(); SBAR();
        stage(Bt, j0, ktd, 1, 0); stage(At, i0, ktd, 1, 1);
        SBAR(); LGKM0(); PRIO1(); MM(bl, 4, 0); PRIO0(); VMW(8); SBAR();
    }

    // --- peeled tail: K-tiles 6,7 — no staging, drain at TP3 ---
    rdA(a0, 0); rdB(b0, 0, bl);
    SBAR(); LGKM0(); PRIO1(); MM(bl, 0, 0); PRIO0(); SBAR();
    rdB(b0, 1, bh);
    SBAR(); LGKM0(); PRIO1(); MM(bh, 0, 2); PRIO0(); SBAR();
    rdA(a0, 1);
    SBAR(); LGKM0(); PRIO1(); MM(bh, 4, 2); PRIO0(); SBAR();
    SBAR(); LGKM0(); PRIO1(); MM(bl, 4, 0); PRIO0(); VMW(0); SBAR();
    rdA(a1, 0); rdB(b1, 0, bl);
    SBAR(); LGKM0(); PRIO1(); MM(bl, 0, 0); PRIO0(); SBAR();
    rdB(b1, 1, bh);
    SBAR(); LGKM0(); PRIO1(); MM(bh, 0, 2); PRIO0(); SBAR();
    rdA(a1, 1);
    SBAR(); LGKM0(); PRIO1(); MM(bh, 4, 2); PRIO0(); SBAR();
    SBAR(); LGKM0(); PRIO1(); MM(bl, 4, 0); PRIO0(); SBAR();

    // ---- fused w3 epilogue: one zg per wave, ring-4 w3 + ring-2 P ----
    char* const opb = smem;                            // 64 pairs x 2048 B
    const int lq = lane >> 4;
    const int zg = wv;                                 // zg = wave -> min w3 traffic
    const int zc = zg * 16 + lrow;

    auto ldW = [&](int ks) -> bf16x8 {
        return *(const bf16x8*)(w3frag + (size_t)((ks * 8 + zg) * 64 + lane) * 8);
    };
    auto ldP = [&](int rg, int ks) -> bf16x8 {
        int row = rg * 16 + lrow;
        int g = ks * 4 + lq;
        int b = g >> 2, jj = g & 3;
        int inner = (b * 64 + jj * 16) ^ (((b >> 1) & 7) << 4) ^ ((row & 7) << 4);
        return *(const bf16x8*)(opb + row * 2048 + inner);
    };

    // early-issue ring-4 w3 loads (L2 latency hides under op-write + sync)
    bf16x8 wR0 = ldW(0), wR1 = ldW(1), wR2 = ldW(2), wR3 = ldW(3);

    // write op tile (scaled, bf16), b-major k2' = b*32+a, 8B vector stores
    const float scale = 1.0f / (float)NB;
    #pragma unroll
    for (int mf = 0; mf < 8; ++mf) {
        #pragma unroll
        for (int nf = 0; nf < 4; ++nf) {
            int col = wc + nf * 16 + lrow;
            int bcol = col & 31;
            int row = wr + mf * 16 + ((lane >> 4) << 2);
            int pl = ((row >> 5) << 3) | (col >> 5);
            int a0e = row & 31;
            int inner = (bcol * 64 + a0e * 2) ^ (((bcol >> 1) & 7) << 4) ^ ((pl & 7) << 4);
            *(uint2*)(opb + pl * 2048 + inner) =
                pack4(f2bf(acc[mf][nf][0] * scale), f2bf(acc[mf][nf][1] * scale),
                      f2bf(acc[mf][nf][2] * scale), f2bf(acc[mf][nf][3] * scale));
        }
    }
    __syncthreads();

    // z-loop: 32 ks; per ks: 4 P-frag LDS reads (ring-2) + 1 w3 read (ring-4)
    // + 4 MFMA. Fully unrolled -> all ring indices static (no scratch).
    f32x4 accP[4] = {};
    bf16x8 pA[4], pB[4];
    #pragma unroll
    for (int r = 0; r < 4; ++r) pA[r] = ldP(r, 0);
    #pragma unroll
    for (int r = 0; r < 4; ++r) pB[r] = ldP(r, 1);

    #pragma unroll
    for (int ks = 0; ks < 32; ++ks) {
        bf16x8 w = ((ks & 3) == 0) ? wR0 : ((ks & 3) == 1) ? wR1
                 : ((ks & 3) == 2) ? wR2 : wR3;
        bf16x8* pc = (ks & 1) ? pB : pA;
        PRIO1();
        accP[0] = __builtin_amdgcn_mfma_f32_16x16x32_bf16(pc[0], w, accP[0], 0, 0, 0);
        accP[1] = __builtin_amdgcn_mfma_f32_16x16x32_bf16(pc[1], w, accP[1], 0, 0, 0);
        accP[2] = __builtin_amdgcn_mfma_f32_16x16x32_bf16(pc[2], w, accP[2], 0, 0, 0);
        accP[3] = __builtin_amdgcn_mfma_f32_16x16x32_bf16(pc[3], w, accP[3], 0, 0, 0);
        PRIO0();
        if (ks + 4 < 32) {
            if ((ks & 3) == 0)      wR0 = ldW(ks + 4);
            else if ((ks & 3) == 1) wR1 = ldW(ks + 4);
            else if ((ks & 3) == 2) wR2 = ldW(ks + 4);
            else                    wR3 = ldW(ks + 4);
        }
        if (ks + 2 < 32) {
            #pragma unroll
            for (int r = 0; r < 4; ++r) pc[r] = ldP(r, ks + 2);
        }
    }

    // write z
    const int pq = (lane >> 4) << 2;
    const float bias = b3[zc];
    #pragma unroll
    for (int pf = 0; pf < 4; ++pf) {
        #pragma unroll
        for (int rr = 0; rr < 4; ++rr) {
            int pl = pf * 16 + pq + rr;
            int ii = (i0 >> 5) + (pl >> 3);
            int jj = (j0 >> 5) + (pl & 7);
            Z[((size_t)ii * L_DIM + jj) * ZD + zc] = accP[pf][rr] + bias;
        }
    }
}

// ---------------------------------------------------------------------------
extern "C" void kernel_launch(void* const* d_in, const int* in_sizes, int n_in,
                              void* d_out, int out_size, void* d_ws, size_t ws_size,
                              hipStream_t stream)
{
    const float* mm    = (const float*)d_in[0];
    const float* gamma = (const float*)d_in[1];
    const float* beta  = (const float*)d_in[2];
    const float* w1    = (const float*)d_in[3];
    const float* b1    = (const float*)d_in[4];
    const float* w2    = (const float*)d_in[5];
    const float* b2    = (const float*)d_in[6];
    const float* w3    = (const float*)d_in[7];
    const float* b3    = (const float*)d_in[8];

    unsigned short* At     = (unsigned short*)d_ws;                  // 12288x512
    unsigned short* Bt     = At + (size_t)MROWS * NB;                // 12288x512
    unsigned short* w3frag = Bt + (size_t)MROWS * NB;                // 131072
    unsigned short* wfrag  = w3frag + 131072;                        // 16384

    prep_kernel<<<576, 256, 0, stream>>>(w1, w2, w3, w3frag, wfrag);
    ln_proj_kernel<<<dim3(16, 192), 256, 0, stream>>>(mm, gamma, beta, wfrag, b1, b2, At, Bt);
    opm_kernel<<<dim3(48, 48), 512, 0, stream>>>(At, Bt, w3frag, b3, (float*)d_out);
}